// Round 6
// baseline (271.985 us; speedup 1.0000x reference)
//
#include <hip/hip_runtime.h>
#include <stdint.h>

// Problem constants
#define Bsz 8
#define Cc  256
#define Crr 32
#define Nn  4096
#define CN  (Cc * Nn)
#define ITILE 128
#define NIT (Nn / ITILE)   // 32
#define JT  32             // j-tile per block
#define PPITCH 136         // P row pitch (u16): 272 B == 16 B mod bank period
#define YPITCH 264         // y^T row pitch (u16)

typedef unsigned short u16;
typedef __attribute__((ext_vector_type(8))) short  short8;
typedef __attribute__((ext_vector_type(4))) float  floatx4;
typedef __attribute__((ext_vector_type(4))) unsigned short u16x4;

__device__ __forceinline__ floatx4 mfma16(short8 a, short8 b, floatx4 c) {
  return __builtin_amdgcn_mfma_f32_16x16x32_bf16(a, b, c, 0, 0, 0);
}
__device__ __forceinline__ u16 f2bf(float f) {
  unsigned int u = __builtin_bit_cast(unsigned int, f);
  u = (u + 0x7FFFu + ((u >> 16) & 1u)) >> 16;   // RNE
  return (u16)u;
}
__device__ __forceinline__ float bf2f(u16 h) {
  unsigned int u = ((unsigned int)h) << 16;
  return __builtin_bit_cast(float, u);
}
__device__ __forceinline__ short8 pack8(const float* __restrict__ p) {
  floatx4 a = *(const floatx4*)p;
  floatx4 b = *(const floatx4*)(p + 4);
  short8 r;
  r[0] = (short)f2bf(a[0]); r[1] = (short)f2bf(a[1]);
  r[2] = (short)f2bf(a[2]); r[3] = (short)f2bf(a[3]);
  r[4] = (short)f2bf(b[0]); r[5] = (short)f2bf(b[1]);
  r[6] = (short)f2bf(b[2]); r[7] = (short)f2bf(b[3]);
  return r;
}
__device__ __forceinline__ void split8(const float* __restrict__ p,
                                       short8& hi, short8& lo) {
  floatx4 a = *(const floatx4*)p;
  floatx4 b = *(const floatx4*)(p + 4);
  float v[8] = {a[0], a[1], a[2], a[3], b[0], b[1], b[2], b[3]};
#pragma unroll
  for (int r = 0; r < 8; ++r) {
    u16 h = f2bf(v[r]);
    hi[r] = (short)h;
    lo[r] = (short)f2bf(v[r] - bf2f(h));
  }
}

// ---------------------------------------------------------------------------
// Kernel 1: projections f,g in split-bf16 (~fp32) precision -> split pairs
// fThi/fTlo, gThi/gTlo in [N][32] frag-ready layout; bf16 w3; tiled bf16 x.
// xb tile layout: tile (i32 x c16), in-tile idx = (c&15)*32 + (i&31) ->
// proj writes 32 B runs, attention PV reads one coalesced b128 per lane.
// ---------------------------------------------------------------------------
template <bool XB16>
__launch_bounds__(256, 4)
__global__ void proj_kernel(const float* __restrict__ x,
                            const float* __restrict__ w1,
                            const float* __restrict__ w2,
                            const float* __restrict__ w3,
                            u16* __restrict__ w3b,
                            u16* __restrict__ fThi, u16* __restrict__ fTlo,
                            u16* __restrict__ gThi, u16* __restrict__ gTlo,
                            u16* __restrict__ xb) {
  const int bid = blockIdx.x;
  const int b   = bid & 7;            // batch pinned to XCD
  const int nt  = bid >> 3;           // 0..127
  const int tid  = threadIdx.x;
  const int w    = tid >> 6;
  const int lane = tid & 63;
  const int m    = lane & 15;
  const int q    = lane >> 4;
  const int nhalf = w >> 1;
  const int chalf = w & 1;
  const int nb   = nt * 32 + nhalf * 16;

  __shared__ float comb[2][16][64];

  const float* xsl = x + (size_t)b * CN;
  const floatx4 z4 = {0.f, 0.f, 0.f, 0.f};
  floatx4 aF[2] = {z4, z4}, aG[2] = {z4, z4};

  for (int ci = 0; ci < 4; ++ci) {
    const int c0 = chalf * 128 + ci * 32;
    const float* xp = xsl + (size_t)(c0 + q * 8) * Nn + nb + m;
    short8 xh, xl;
#pragma unroll
    for (int r = 0; r < 8; ++r) {
      float v = xp[(size_t)r * Nn];
      u16 h = f2bf(v);
      xh[r] = (short)h;
      xl[r] = (short)f2bf(v - bf2f(h));
    }
    if (XB16) {
      const int n = nb + m;
      const size_t tb = (size_t)b * CN;
#pragma unroll
      for (int r = 0; r < 8; ++r) {
        int c = c0 + q * 8 + r;
        xb[tb + ((size_t)((n >> 5) * 16 + (c >> 4)) << 9) +
           (c & 15) * 32 + (n & 31)] = (u16)xh[r];
      }
    }
#pragma unroll
    for (int ot = 0; ot < 2; ++ot) {
      short8 wh, wl;
      split8(w1 + (size_t)(ot * 16 + m) * Cc + c0 + q * 8, wh, wl);
      aF[ot] = mfma16(xh, wh, aF[ot]);
      aF[ot] = mfma16(xh, wl, aF[ot]);
      aF[ot] = mfma16(xl, wh, aF[ot]);
      split8(w2 + (size_t)(ot * 16 + m) * Cc + c0 + q * 8, wh, wl);
      aG[ot] = mfma16(xh, wh, aG[ot]);
      aG[ot] = mfma16(xh, wl, aG[ot]);
      aG[ot] = mfma16(xl, wh, aG[ot]);
    }
  }

  if (chalf) {
#pragma unroll
    for (int k = 0; k < 2; ++k)
#pragma unroll
      for (int r = 0; r < 4; ++r) {
        comb[nhalf][k * 4 + r][lane]     = aF[k][r];
        comb[nhalf][8 + k * 4 + r][lane] = aG[k][r];
      }
  }
  __syncthreads();
  if (!chalf) {
#pragma unroll
    for (int ot = 0; ot < 2; ++ot)
#pragma unroll
      for (int r = 0; r < 4; ++r) {
        float vf = aF[ot][r] + comb[nhalf][ot * 4 + r][lane];
        float vg = aG[ot][r] + comb[nhalf][8 + ot * 4 + r][lane];
        int n = nb + q * 4 + r;
        size_t idx = ((size_t)b * Nn + n) * Crr + ot * 16 + m;
        u16 hf = f2bf(vf);
        fThi[idx] = hf;
        fTlo[idx] = f2bf(vf - bf2f(hf));
        u16 hg = f2bf(vg);
        gThi[idx] = hg;
        gTlo[idx] = f2bf(vg - bf2f(hg));
      }
  }
  if (bid < 64) {
    int base = bid * 1024 + tid * 4;
    floatx4 v = *(const floatx4*)(w3 + base);
    u16x4 o;
    o[0] = f2bf(v[0]); o[1] = f2bf(v[1]); o[2] = f2bf(v[2]); o[3] = f2bf(v[3]);
    *(u16x4*)(w3b + base) = o;
  }
}

// ---------------------------------------------------------------------------
// Kernel 2: fused attention + channel-mix. j-tile 32, 256 threads (4 waves),
// grid 1024 -> 4 INDEPENDENT blocks per CU (decorrelated barrier groups).
//   y = x . softmax_cols(f^T g);  out = w3 . y + x
// Wave w: i-strip of 32 for S (2 sub-strips), c-strip of 64 for PV/mix.
// i-tile 128, dbuf P, ONE barrier/iter; S(t+1) after the barrier overlaps
// PV(t). P pitch 136 u16: b128 reads at the 8/bank floor, b64 writes at 4.
// ---------------------------------------------------------------------------
template <bool XB16>
__launch_bounds__(256, 4)
__global__ void attn_kernel(const u16* __restrict__ fThi,
                            const u16* __restrict__ fTlo,
                            const u16* __restrict__ gThi,
                            const u16* __restrict__ gTlo,
                            const u16* __restrict__ xb,
                            const float* __restrict__ x,
                            const u16* __restrict__ w3b,
                            float* __restrict__ out) {
  const int bid = blockIdx.x;
  const int b   = bid & 7;
  const int jt  = bid >> 3;           // 0..127
  const int j0  = jt * JT;
  const int tid  = threadIdx.x;
  const int w    = tid >> 6;          // 0..3
  const int lane = tid & 63;
  const int m    = lane & 15;
  const int q    = lane >> 4;

  __shared__ u16   P[2 * JT * PPITCH];   // 17.4 KB; reused as y^T in epilogue
  __shared__ float lred[16 * JT];
  __shared__ float linv[JT];

  const size_t fgb = (size_t)b * (size_t)Nn * Crr;
  const u16*   xbs = xb + (size_t)b * CN;
  const float* xfs = x + (size_t)b * CN;

  short8 bgh[2], bgl[2];   // g fragments (loop-invariant): B[k=o][n=j]
#pragma unroll
  for (int jb = 0; jb < 2; ++jb) {
    size_t idx = fgb + (size_t)(j0 + jb * 16 + m) * Crr + q * 8;
    bgh[jb] = *(const short8*)(gThi + idx);
    bgl[jb] = *(const short8*)(gTlo + idx);
  }

  const floatx4 z4 = {0.f, 0.f, 0.f, 0.f};
  floatx4 acc[4][2];   // [cb][jb]: c = (w*4+cb)*16 + q*4+r, j = j0+jb*16+m
#pragma unroll
  for (int cb = 0; cb < 4; ++cb)
#pragma unroll
    for (int jb = 0; jb < 2; ++jb) acc[cb][jb] = z4;

  float ps[2] = {0.f, 0.f};
  unsigned int pw[2][2][2];   // [isub][jb][pair]

  // split-precision scores for the wave's 32-i strip of tile t
  auto computeS = [&](int t) {
#pragma unroll
    for (int isub = 0; isub < 2; ++isub) {
      const int ig = t * ITILE + w * 32 + isub * 16 + m;
      size_t fidx = fgb + (size_t)ig * Crr + q * 8;
      short8 afh = *(const short8*)(fThi + fidx);
      short8 afl = *(const short8*)(fTlo + fidx);
#pragma unroll
      for (int jb = 0; jb < 2; ++jb) {
        floatx4 t3 = mfma16(afl, bgh[jb], z4);
        t3 = mfma16(afh, bgl[jb], t3);
        t3 = mfma16(afh, bgh[jb], t3);
        u16 h0 = f2bf(__expf(t3[0]));
        u16 h1 = f2bf(__expf(t3[1]));
        u16 h2 = f2bf(__expf(t3[2]));
        u16 h3 = f2bf(__expf(t3[3]));
        ps[jb] += (bf2f(h0) + bf2f(h1)) + (bf2f(h2) + bf2f(h3));
        pw[isub][jb][0] = (unsigned int)h0 | ((unsigned int)h1 << 16);
        pw[isub][jb][1] = (unsigned int)h2 | ((unsigned int)h3 << 16);
      }
    }
  };

  computeS(0);

  for (int t = 0; t < NIT; ++t) {
    u16* buf = P + (t & 1) * (JT * PPITCH);
    // write P(t): lane rows i_loc = w*32 + isub*16 + q*4+r
#pragma unroll
    for (int isub = 0; isub < 2; ++isub) {
      const int gr = w * 4 + isub * 2 + (q >> 1);
#pragma unroll
      for (int jb = 0; jb < 2; ++jb) {
        const int j = jb * 16 + m;
        *(uint2*)(buf + j * PPITCH + gr * 8 + (q & 1) * 4) =
            make_uint2(pw[isub][jb][0], pw[isub][jb][1]);
      }
    }
    __syncthreads();

    if (t + 1 < NIT) computeS(t + 1);   // overlaps PV(t)

    // PV(t): A = x tiles (c-strip 64 per wave), B = P from LDS
#pragma unroll
    for (int kk = 0; kk < 4; ++kk) {
      short8 bp[2];
#pragma unroll
      for (int jb = 0; jb < 2; ++jb)
        bp[jb] = *(const short8*)(buf + (jb * 16 + m) * PPITCH + (kk * 4 + q) * 8);
#pragma unroll
      for (int cb = 0; cb < 4; ++cb) {
        short8 ah;
        if (XB16) {
          const int tile = (t * 4 + kk) * 16 + (w * 4 + cb);
          ah = *(const short8*)(xbs + ((size_t)tile << 9) + m * 32 + q * 8);
        } else {
          ah = pack8(xfs + (size_t)((w * 4 + cb) * 16 + m) * Nn +
                     t * ITILE + kk * 32 + q * 8);
        }
#pragma unroll
        for (int jb = 0; jb < 2; ++jb)
          acc[cb][jb] = mfma16(ah, bp[jb], acc[cb][jb]);
      }
    }
  }

  // ---- softmax denominator (16 partials per j column) ----
#pragma unroll
  for (int jb = 0; jb < 2; ++jb)
    lred[(w * 4 + q) * JT + jb * 16 + m] = ps[jb];
  __syncthreads();
  if (tid < JT) {
    float s = 0.f;
#pragma unroll
    for (int t2 = 0; t2 < 16; ++t2) s += lred[t2 * JT + tid];
    linv[tid] = 1.0f / s;
  }
  __syncthreads();

  // ---- y^T (scaled, bf16) into LDS: rows j (32) x 256 c, pitch 264 ----
  u16* yt = P;
#pragma unroll
  for (int cb = 0; cb < 4; ++cb)
#pragma unroll
    for (int jb = 0; jb < 2; ++jb) {
      const int j = jb * 16 + m;
      const float li = linv[j];
      unsigned int d0 = (unsigned int)f2bf(acc[cb][jb][0] * li) |
                        ((unsigned int)f2bf(acc[cb][jb][1] * li) << 16);
      unsigned int d1 = (unsigned int)f2bf(acc[cb][jb][2] * li) |
                        ((unsigned int)f2bf(acc[cb][jb][3] * li) << 16);
      *(uint2*)(yt + j * YPITCH + (w * 4 + cb) * 16 + q * 4) = make_uint2(d0, d1);
    }
  __syncthreads();

  // ---- channel mix: out = w3 . y + x ----
  floatx4 macc[4][2];
#pragma unroll
  for (int ct = 0; ct < 4; ++ct)
#pragma unroll
    for (int jb = 0; jb < 2; ++jb) macc[ct][jb] = z4;

  for (int k0 = 0; k0 < Cc; k0 += 32) {
    short8 bf_[2];
#pragma unroll
    for (int jb = 0; jb < 2; ++jb)
      bf_[jb] = *(const short8*)(yt + (jb * 16 + m) * YPITCH + k0 + q * 8);
#pragma unroll
    for (int ct = 0; ct < 4; ++ct) {
      short8 aw = *(const short8*)(w3b + (size_t)((w * 4 + ct) * 16 + m) * Cc +
                                   k0 + q * 8);
#pragma unroll
      for (int jb = 0; jb < 2; ++jb)
        macc[ct][jb] = mfma16(aw, bf_[jb], macc[ct][jb]);
    }
  }

  float* osl = out + (size_t)b * CN;
#pragma unroll
  for (int ct = 0; ct < 4; ++ct)
#pragma unroll
    for (int jb = 0; jb < 2; ++jb)
#pragma unroll
      for (int r = 0; r < 4; ++r) {
        const int c = (w * 4 + ct) * 16 + q * 4 + r;
        const size_t idx = (size_t)c * Nn + j0 + jb * 16 + m;
        osl[idx] = macc[ct][jb][r] + xfs[idx];
      }
}

extern "C" void kernel_launch(void* const* d_in, const int* in_sizes, int n_in,
                              void* d_out, int out_size, void* d_ws, size_t ws_size,
                              hipStream_t stream) {
  const float* x  = (const float*)d_in[0];
  const float* w1 = (const float*)d_in[1];
  const float* w2 = (const float*)d_in[2];
  const float* w3 = (const float*)d_in[3];
  float* out = (float*)d_out;

  // ws (bf16 elements): w3b 64K | fThi 1M | fTlo 1M | gThi 1M | gTlo 1M | xb 8M
  const size_t FG = (size_t)Bsz * Nn * Crr;
  u16* w3b  = (u16*)d_ws;
  u16* fThi = w3b + (size_t)Cc * Cc;
  u16* fTlo = fThi + FG;
  u16* gThi = fTlo + FG;
  u16* gTlo = gThi + FG;
  u16* xb   = gTlo + FG;
  const size_t need_xb = ((size_t)Cc * Cc + 4 * FG + (size_t)Bsz * CN) * 2;
  const bool use_xb = ws_size >= need_xb;

  if (use_xb) {
    proj_kernel<true><<<dim3(1024), dim3(256), 0, stream>>>(
        x, w1, w2, w3, w3b, fThi, fTlo, gThi, gTlo, xb);
    attn_kernel<true><<<dim3(1024), dim3(256), 0, stream>>>(
        fThi, fTlo, gThi, gTlo, xb, x, w3b, out);
  } else {
    proj_kernel<false><<<dim3(1024), dim3(256), 0, stream>>>(
        x, w1, w2, w3, w3b, fThi, fTlo, gThi, gTlo, xb);
    attn_kernel<false><<<dim3(1024), dim3(256), 0, stream>>>(
        fThi, fTlo, gThi, gTlo, xb, x, w3b, out);
  }
}

// Round 7
// 215.959 us; speedup vs baseline: 1.2594x; 1.2594x over previous
//
#include <hip/hip_runtime.h>
#include <stdint.h>

// Problem constants
#define Bsz 8
#define Cc  256
#define Crr 32
#define Nn  4096
#define CN  (Cc * Nn)
#define ITILE 128
#define NIT (Nn / ITILE)   // 32
#define PPITCH 136         // P row pitch (u16): at bank floor for b64 w / b128 r
#define YPITCH 264         // y^T row pitch (u16)

typedef unsigned short u16;
typedef __attribute__((ext_vector_type(8))) short  short8;
typedef __attribute__((ext_vector_type(4))) float  floatx4;
typedef __attribute__((ext_vector_type(4))) unsigned short u16x4;

__device__ __forceinline__ floatx4 mfma16(short8 a, short8 b, floatx4 c) {
  return __builtin_amdgcn_mfma_f32_16x16x32_bf16(a, b, c, 0, 0, 0);
}
__device__ __forceinline__ u16 f2bf(float f) {
  unsigned int u = __builtin_bit_cast(unsigned int, f);
  u = (u + 0x7FFFu + ((u >> 16) & 1u)) >> 16;   // RNE
  return (u16)u;
}
__device__ __forceinline__ float bf2f(u16 h) {
  unsigned int u = ((unsigned int)h) << 16;
  return __builtin_bit_cast(float, u);
}
__device__ __forceinline__ short8 pack8(const float* __restrict__ p) {
  floatx4 a = *(const floatx4*)p;
  floatx4 b = *(const floatx4*)(p + 4);
  short8 r;
  r[0] = (short)f2bf(a[0]); r[1] = (short)f2bf(a[1]);
  r[2] = (short)f2bf(a[2]); r[3] = (short)f2bf(a[3]);
  r[4] = (short)f2bf(b[0]); r[5] = (short)f2bf(b[1]);
  r[6] = (short)f2bf(b[2]); r[7] = (short)f2bf(b[3]);
  return r;
}
__device__ __forceinline__ void split8(const float* __restrict__ p,
                                       short8& hi, short8& lo) {
  floatx4 a = *(const floatx4*)p;
  floatx4 b = *(const floatx4*)(p + 4);
  float v[8] = {a[0], a[1], a[2], a[3], b[0], b[1], b[2], b[3]};
#pragma unroll
  for (int r = 0; r < 8; ++r) {
    u16 h = f2bf(v[r]);
    hi[r] = (short)h;
    lo[r] = (short)f2bf(v[r] - bf2f(h));
  }
}

// ---------------------------------------------------------------------------
// Kernel 1: projections f,g in split-bf16 (~fp32) precision -> split pairs
// in [N][32] frag-ready layout; bf16 w3; tiled bf16 x (tile i32 x c16,
// in-tile idx (c&15)*32 + (i&31)). Grid 2048: block = (batch, n-tile 16);
// wave w owns c-quarter w*64..w*64+63 (2 chunks of 32); 4-way LDS combine.
// ---------------------------------------------------------------------------
template <bool XB16>
__launch_bounds__(256, 4)
__global__ void proj_kernel(const float* __restrict__ x,
                            const float* __restrict__ w1,
                            const float* __restrict__ w2,
                            const float* __restrict__ w3,
                            u16* __restrict__ w3b,
                            u16* __restrict__ fThi, u16* __restrict__ fTlo,
                            u16* __restrict__ gThi, u16* __restrict__ gTlo,
                            u16* __restrict__ xb) {
  const int bid = blockIdx.x;
  const int b   = bid & 7;            // batch pinned to XCD
  const int nt  = bid >> 3;           // 0..255
  const int tid  = threadIdx.x;
  const int w    = tid >> 6;          // c-quarter
  const int lane = tid & 63;
  const int m    = lane & 15;
  const int q    = lane >> 4;
  const int nb   = nt * 16;

  __shared__ float comb[3][16][64];   // partials from waves 1..3

  const float* xsl = x + (size_t)b * CN;
  const floatx4 z4 = {0.f, 0.f, 0.f, 0.f};
  floatx4 aF[2] = {z4, z4}, aG[2] = {z4, z4};

  for (int ci = 0; ci < 2; ++ci) {
    const int c0 = w * 64 + ci * 32;
    const float* xp = xsl + (size_t)(c0 + q * 8) * Nn + nb + m;
    short8 xh, xl;
#pragma unroll
    for (int r = 0; r < 8; ++r) {
      float v = xp[(size_t)r * Nn];
      u16 h = f2bf(v);
      xh[r] = (short)h;
      xl[r] = (short)f2bf(v - bf2f(h));
    }
    if (XB16) {
      const int n = nb + m;
      const size_t tb = (size_t)b * CN;
#pragma unroll
      for (int r = 0; r < 8; ++r) {
        int c = c0 + q * 8 + r;
        xb[tb + ((size_t)((n >> 5) * 16 + (c >> 4)) << 9) +
           (c & 15) * 32 + (n & 31)] = (u16)xh[r];
      }
    }
#pragma unroll
    for (int ot = 0; ot < 2; ++ot) {
      short8 wh, wl;
      split8(w1 + (size_t)(ot * 16 + m) * Cc + c0 + q * 8, wh, wl);
      aF[ot] = mfma16(xh, wh, aF[ot]);
      aF[ot] = mfma16(xh, wl, aF[ot]);
      aF[ot] = mfma16(xl, wh, aF[ot]);
      split8(w2 + (size_t)(ot * 16 + m) * Cc + c0 + q * 8, wh, wl);
      aG[ot] = mfma16(xh, wh, aG[ot]);
      aG[ot] = mfma16(xh, wl, aG[ot]);
      aG[ot] = mfma16(xl, wh, aG[ot]);
    }
  }

  if (w > 0) {
#pragma unroll
    for (int k = 0; k < 2; ++k)
#pragma unroll
      for (int r = 0; r < 4; ++r) {
        comb[w - 1][k * 4 + r][lane]     = aF[k][r];
        comb[w - 1][8 + k * 4 + r][lane] = aG[k][r];
      }
  }
  __syncthreads();
  if (w == 0) {
#pragma unroll
    for (int ot = 0; ot < 2; ++ot)
#pragma unroll
      for (int r = 0; r < 4; ++r) {
        float vf = aF[ot][r] + comb[0][ot * 4 + r][lane] +
                   comb[1][ot * 4 + r][lane] + comb[2][ot * 4 + r][lane];
        float vg = aG[ot][r] + comb[0][8 + ot * 4 + r][lane] +
                   comb[1][8 + ot * 4 + r][lane] + comb[2][8 + ot * 4 + r][lane];
        int n = nb + q * 4 + r;
        size_t idx = ((size_t)b * Nn + n) * Crr + ot * 16 + m;
        u16 hf = f2bf(vf);
        fThi[idx] = hf;
        fTlo[idx] = f2bf(vf - bf2f(hf));
        u16 hg = f2bf(vg);
        gThi[idx] = hg;
        gTlo[idx] = f2bf(vg - bf2f(hg));
      }
  }
  if (bid < 64) {
    int base = bid * 1024 + tid * 4;
    floatx4 v = *(const floatx4*)(w3 + base);
    u16x4 o;
    o[0] = f2bf(v[0]); o[1] = f2bf(v[1]); o[2] = f2bf(v[2]); o[3] = f2bf(v[3]);
    *(u16x4*)(w3b + base) = o;
  }
}

// ---------------------------------------------------------------------------
// Kernel 2: fused attention + channel-mix, 512 threads, grid 512 (j-tile 64).
//   y = x . softmax_cols(f^T g);  out = w3 . y + x
// K-loop, per iteration (ONE barrier):
//   write P(t) -> barrier -> prefetch f(t+2) -> fused kk loop:
//     [bp reads, 8 PV(t) MFMAs, S(t+1) jb=kk: 3 MFMAs + exp + pack]
// Source-level S/PV interleave makes the in-order wave alternate pipes;
// f prefetch is consumed one iteration later so its latency (and the
// barrier's vmcnt drain) never sit on the critical path.
// ---------------------------------------------------------------------------
template <bool XB16>
__launch_bounds__(512, 4)
__global__ void attn_kernel(const u16* __restrict__ fThi,
                            const u16* __restrict__ fTlo,
                            const u16* __restrict__ gThi,
                            const u16* __restrict__ gTlo,
                            const u16* __restrict__ xb,
                            const float* __restrict__ x,
                            const u16* __restrict__ w3b,
                            float* __restrict__ out) {
  const int bid = blockIdx.x;
  const int b   = bid & 7;
  const int jt  = bid >> 3;
  const int j0  = jt * 64;
  const int tid  = threadIdx.x;
  const int w    = tid >> 6;          // 0..7
  const int lane = tid & 63;
  const int m    = lane & 15;
  const int q    = lane >> 4;

  __shared__ u16   P[2 * 64 * PPITCH];   // 34 KB; reused as y^T in epilogue
  __shared__ float lred[32 * 64];
  __shared__ float linv[64];

  const size_t fgb = (size_t)b * (size_t)Nn * Crr;
  const u16*   xbs = xb + (size_t)b * CN;
  const float* xfs = x + (size_t)b * CN;

  short8 bgh[4], bgl[4];   // g fragments (loop-invariant)
#pragma unroll
  for (int jb = 0; jb < 4; ++jb) {
    size_t idx = fgb + (size_t)(j0 + jb * 16 + m) * Crr + q * 8;
    bgh[jb] = *(const short8*)(gThi + idx);
    bgl[jb] = *(const short8*)(gTlo + idx);
  }

  const floatx4 z4 = {0.f, 0.f, 0.f, 0.f};
  floatx4 acc[2][4];   // [cb][jb]: c = (w*2+cb)*16 + q*4+r, j = j0+jb*16+m
#pragma unroll
  for (int cb = 0; cb < 2; ++cb)
#pragma unroll
    for (int jb = 0; jb < 4; ++jb) acc[cb][jb] = z4;

  float ps[4] = {0.f, 0.f, 0.f, 0.f};
  unsigned int pw[4][2];
  short8 fAh, fAl, fBh, fBl;   // f frags: A = for S(t+1), B = prefetch

  // one S jb-group: 3 MFMAs + exp + pack into pw[jb], accumulate ps[jb]
  auto sPart = [&](int jb) {
    floatx4 t3 = mfma16(fAl, bgh[jb], z4);
    t3 = mfma16(fAh, bgl[jb], t3);
    t3 = mfma16(fAh, bgh[jb], t3);
    u16 h0 = f2bf(__expf(t3[0]));
    u16 h1 = f2bf(__expf(t3[1]));
    u16 h2 = f2bf(__expf(t3[2]));
    u16 h3 = f2bf(__expf(t3[3]));
    ps[jb] += (bf2f(h0) + bf2f(h1)) + (bf2f(h2) + bf2f(h3));
    pw[jb][0] = (unsigned int)h0 | ((unsigned int)h1 << 16);
    pw[jb][1] = (unsigned int)h2 | ((unsigned int)h3 << 16);
  };

  // prologue: S(0) computed directly; fA <- f(1)
  {
    size_t fidx = fgb + (size_t)(w * 16 + m) * Crr + q * 8;
    fAh = *(const short8*)(fThi + fidx);
    fAl = *(const short8*)(fTlo + fidx);
#pragma unroll
    for (int jb = 0; jb < 4; ++jb) sPart(jb);
    size_t f1 = fgb + (size_t)(ITILE + w * 16 + m) * Crr + q * 8;
    fAh = *(const short8*)(fThi + f1);
    fAl = *(const short8*)(fTlo + f1);
  }

  const int gr = w * 2 + (q >> 1);
  for (int t = 0; t < NIT - 1; ++t) {
    u16* buf = P + (t & 1) * (64 * PPITCH);
#pragma unroll
    for (int jb = 0; jb < 4; ++jb) {
      const int j = jb * 16 + m;
      *(uint2*)(buf + j * PPITCH + gr * 8 + (q & 1) * 4) =
          make_uint2(pw[jb][0], pw[jb][1]);
    }
    __syncthreads();

    // prefetch f(t+2): consumed NEXT iteration -> latency fully hidden
    if (t + 2 < NIT) {
      size_t fidx = fgb + (size_t)((t + 2) * ITILE + w * 16 + m) * Crr + q * 8;
      fBh = *(const short8*)(fThi + fidx);
      fBl = *(const short8*)(fTlo + fidx);
    }

    // fused PV(t) + S(t+1), interleaved at kk granularity
#pragma unroll
    for (int kk = 0; kk < 4; ++kk) {
      short8 bp[4];
#pragma unroll
      for (int jb = 0; jb < 4; ++jb)
        bp[jb] = *(const short8*)(buf + (jb * 16 + m) * PPITCH + (kk * 4 + q) * 8);
#pragma unroll
      for (int cb = 0; cb < 2; ++cb) {
        short8 ah;
        if (XB16) {
          const int tile = (t * 4 + kk) * 16 + (w * 2 + cb);
          ah = *(const short8*)(xbs + ((size_t)tile << 9) + m * 32 + q * 8);
        } else {
          ah = pack8(xfs + (size_t)(((w * 2 + cb) * 16 + m)) * Nn +
                     t * ITILE + kk * 32 + q * 8);
        }
#pragma unroll
        for (int jb = 0; jb < 4; ++jb)
          acc[cb][jb] = mfma16(ah, bp[jb], acc[cb][jb]);
      }
      sPart(kk);   // S(t+1) slice — overlaps the PV MFMAs above
    }
    fAh = fBh; fAl = fBl;
  }

  // final iteration: PV only
  {
    const int t = NIT - 1;
    u16* buf = P + (t & 1) * (64 * PPITCH);
#pragma unroll
    for (int jb = 0; jb < 4; ++jb) {
      const int j = jb * 16 + m;
      *(uint2*)(buf + j * PPITCH + gr * 8 + (q & 1) * 4) =
          make_uint2(pw[jb][0], pw[jb][1]);
    }
    __syncthreads();
#pragma unroll
    for (int kk = 0; kk < 4; ++kk) {
      short8 bp[4];
#pragma unroll
      for (int jb = 0; jb < 4; ++jb)
        bp[jb] = *(const short8*)(buf + (jb * 16 + m) * PPITCH + (kk * 4 + q) * 8);
#pragma unroll
      for (int cb = 0; cb < 2; ++cb) {
        short8 ah;
        if (XB16) {
          const int tile = (t * 4 + kk) * 16 + (w * 2 + cb);
          ah = *(const short8*)(xbs + ((size_t)tile << 9) + m * 32 + q * 8);
        } else {
          ah = pack8(xfs + (size_t)(((w * 2 + cb) * 16 + m)) * Nn +
                     t * ITILE + kk * 32 + q * 8);
        }
#pragma unroll
        for (int jb = 0; jb < 4; ++jb)
          acc[cb][jb] = mfma16(ah, bp[jb], acc[cb][jb]);
      }
    }
  }

  // ---- softmax denominator ----
#pragma unroll
  for (int jb = 0; jb < 4; ++jb)
    lred[(w * 4 + q) * 64 + jb * 16 + m] = ps[jb];
  __syncthreads();
  if (tid < 64) {
    float s = 0.f;
#pragma unroll
    for (int t2 = 0; t2 < 32; ++t2) s += lred[t2 * 64 + tid];
    linv[tid] = 1.0f / s;
  }
  __syncthreads();

  // ---- y^T (scaled, bf16) into LDS: rows j (64) x 256 c, pitch 264 ----
  u16* yt = P;
#pragma unroll
  for (int cb = 0; cb < 2; ++cb)
#pragma unroll
    for (int jb = 0; jb < 4; ++jb) {
      const int j = jb * 16 + m;
      const float li = linv[j];
      unsigned int d0 = (unsigned int)f2bf(acc[cb][jb][0] * li) |
                        ((unsigned int)f2bf(acc[cb][jb][1] * li) << 16);
      unsigned int d1 = (unsigned int)f2bf(acc[cb][jb][2] * li) |
                        ((unsigned int)f2bf(acc[cb][jb][3] * li) << 16);
      *(uint2*)(yt + j * YPITCH + (w * 2 + cb) * 16 + q * 4) = make_uint2(d0, d1);
    }
  __syncthreads();

  // ---- channel mix: out = w3 . y + x ----
  floatx4 macc[2][4];
#pragma unroll
  for (int ct = 0; ct < 2; ++ct)
#pragma unroll
    for (int jb = 0; jb < 4; ++jb) macc[ct][jb] = z4;

  for (int k0 = 0; k0 < Cc; k0 += 32) {
    short8 bf_[4];
#pragma unroll
    for (int jb = 0; jb < 4; ++jb)
      bf_[jb] = *(const short8*)(yt + (jb * 16 + m) * YPITCH + k0 + q * 8);
#pragma unroll
    for (int ct = 0; ct < 2; ++ct) {
      short8 aw = *(const short8*)(w3b + (size_t)((w * 2 + ct) * 16 + m) * Cc +
                                   k0 + q * 8);
#pragma unroll
      for (int jb = 0; jb < 4; ++jb)
        macc[ct][jb] = mfma16(aw, bf_[jb], macc[ct][jb]);
    }
  }

  float* osl = out + (size_t)b * CN;
#pragma unroll
  for (int ct = 0; ct < 2; ++ct)
#pragma unroll
    for (int jb = 0; jb < 4; ++jb)
#pragma unroll
      for (int r = 0; r < 4; ++r) {
        const int c = (w * 2 + ct) * 16 + q * 4 + r;
        const size_t idx = (size_t)c * Nn + j0 + jb * 16 + m;
        osl[idx] = macc[ct][jb][r] + xfs[idx];
      }
}

extern "C" void kernel_launch(void* const* d_in, const int* in_sizes, int n_in,
                              void* d_out, int out_size, void* d_ws, size_t ws_size,
                              hipStream_t stream) {
  const float* x  = (const float*)d_in[0];
  const float* w1 = (const float*)d_in[1];
  const float* w2 = (const float*)d_in[2];
  const float* w3 = (const float*)d_in[3];
  float* out = (float*)d_out;

  // ws (bf16 elements): w3b 64K | fThi 1M | fTlo 1M | gThi 1M | gTlo 1M | xb 8M
  const size_t FG = (size_t)Bsz * Nn * Crr;
  u16* w3b  = (u16*)d_ws;
  u16* fThi = w3b + (size_t)Cc * Cc;
  u16* fTlo = fThi + FG;
  u16* gThi = fTlo + FG;
  u16* gTlo = gThi + FG;
  u16* xb   = gTlo + FG;
  const size_t need_xb = ((size_t)Cc * Cc + 4 * FG + (size_t)Bsz * CN) * 2;
  const bool use_xb = ws_size >= need_xb;

  if (use_xb) {
    proj_kernel<true><<<dim3(2048), dim3(256), 0, stream>>>(
        x, w1, w2, w3, w3b, fThi, fTlo, gThi, gTlo, xb);
    attn_kernel<true><<<dim3(512), dim3(512), 0, stream>>>(
        fThi, fTlo, gThi, gTlo, xb, x, w3b, out);
  } else {
    proj_kernel<false><<<dim3(2048), dim3(256), 0, stream>>>(
        x, w1, w2, w3, w3b, fThi, fTlo, gThi, gTlo, xb);
    attn_kernel<false><<<dim3(512), dim3(512), 0, stream>>>(
        fThi, fTlo, gThi, gTlo, xb, x, w3b, out);
  }
}